// Round 3
// baseline (183.523 us; speedup 1.0000x reference)
//
#include <hip/hip_runtime.h>

#define BB   128          // batch
#define NN   1024         // vocab / matrix dim
#define RPB  16           // blocks per batch
#define ROWS (NN / RPB)   // 64 rows of K per block
#define PF   8            // prefetched rows issued before softmax prologue

typedef float f4 __attribute__((ext_vector_type(4)));

// ---------------------------------------------------------------------------
// Fully fused kernel.  Block (b, rb):
//   1. issues PF non-temporal row-loads of its K slice (hides prologue),
//   2. recomputes softmax(m[b]) (4 KB, L2-resident across the 16 blocks),
//   3. streams its 64-row K slice accumulating sum k[n,m]*p[n]*(d(n,m)-p[m]),
//   4. publishes its partial with release semantics; the 16th arriver of the
//      batch (device-scope atomic counter) combines partials + ce -> out[b].
// Counter is zeroed by a stream-ordered memset in kernel_launch each call.
// ---------------------------------------------------------------------------
__global__ __launch_bounds__(256) void fused_all_kernel(
    const float* __restrict__ m, const float* __restrict__ k,
    const int* __restrict__ targets,
    float* __restrict__ ce, float* __restrict__ partial,
    unsigned int* __restrict__ cnt, float* __restrict__ out)
{
    const int blk = blockIdx.x;
    const int b   = blk >> 4;        // blk / RPB
    const int rb  = blk & (RPB - 1); // blk % RPB
    const int tid = threadIdx.x;

    __shared__ float sp[NN];
    __shared__ float sred[4];

    const float* mb = m + (size_t)b * NN;
    float4 v = reinterpret_cast<const float4*>(mb)[tid];

    // ---- issue K prefetch before the softmax reductions ----
    const int n0 = rb * ROWS;
    const f4* kp = reinterpret_cast<const f4*>(k + ((size_t)b * NN + n0) * NN) + tid;
    f4 kpre[PF];
    #pragma unroll
    for (int j = 0; j < PF; ++j)
        kpre[j] = __builtin_nontemporal_load(kp + (size_t)j * (NN / 4));

    // ---- softmax over m[b] ----
    float mx = fmaxf(fmaxf(v.x, v.y), fmaxf(v.z, v.w));
    #pragma unroll
    for (int off = 32; off > 0; off >>= 1) mx = fmaxf(mx, __shfl_down(mx, off));
    if ((tid & 63) == 0) sred[tid >> 6] = mx;
    __syncthreads();
    mx = fmaxf(fmaxf(sred[0], sred[1]), fmaxf(sred[2], sred[3]));
    __syncthreads();

    float e0 = expf(v.x - mx), e1 = expf(v.y - mx);
    float e2 = expf(v.z - mx), e3 = expf(v.w - mx);
    float s = (e0 + e1) + (e2 + e3);
    #pragma unroll
    for (int off = 32; off > 0; off >>= 1) s += __shfl_down(s, off);
    if ((tid & 63) == 0) sred[tid >> 6] = s;
    __syncthreads();
    s = (sred[0] + sred[1]) + (sred[2] + sred[3]);

    const float inv = 1.0f / s;
    const float pm0 = e0 * inv, pm1 = e1 * inv, pm2 = e2 * inv, pm3 = e3 * inv;
    reinterpret_cast<float4*>(sp)[tid] = make_float4(pm0, pm1, pm2, pm3);
    __syncthreads();

    if (rb == 0 && tid == 0)
        __hip_atomic_store(&ce[b], mx + logf(s) - mb[targets[b]],
                           __ATOMIC_RELAXED, __HIP_MEMORY_SCOPE_AGENT);

    // ---- consume prefetched rows ----
    const int m0 = 4 * tid;
    float acc = 0.0f;
    #pragma unroll
    for (int j = 0; j < PF; ++j) {
        const int n = n0 + j;
        f4    k4 = kpre[j];
        float pn = sp[n];
        float d0 = (n == m0    ) ? 1.0f : 0.0f;
        float d1 = (n == m0 + 1) ? 1.0f : 0.0f;
        float d2 = (n == m0 + 2) ? 1.0f : 0.0f;
        float d3 = (n == m0 + 3) ? 1.0f : 0.0f;
        acc += pn * (k4.x * (d0 - pm0) + k4.y * (d1 - pm1) +
                     k4.z * (d2 - pm2) + k4.w * (d3 - pm3));
    }

    // ---- stream remaining 56 rows ----
    #pragma unroll 8
    for (int i = PF; i < ROWS; ++i) {
        const int n = n0 + i;
        f4    k4 = __builtin_nontemporal_load(kp + (size_t)i * (NN / 4));
        float pn = sp[n];
        float d0 = (n == m0    ) ? 1.0f : 0.0f;
        float d1 = (n == m0 + 1) ? 1.0f : 0.0f;
        float d2 = (n == m0 + 2) ? 1.0f : 0.0f;
        float d3 = (n == m0 + 3) ? 1.0f : 0.0f;
        acc += pn * (k4.x * (d0 - pm0) + k4.y * (d1 - pm1) +
                     k4.z * (d2 - pm2) + k4.w * (d3 - pm3));
    }

    // ---- block reduce ----
    #pragma unroll
    for (int off = 32; off > 0; off >>= 1) acc += __shfl_down(acc, off);
    __syncthreads();   // sred reuse safety
    if ((tid & 63) == 0) sred[tid >> 6] = acc;
    __syncthreads();

    // ---- publish partial; 16th arriver finalizes the batch ----
    if (tid == 0) {
        float bs = (sred[0] + sred[1]) + (sred[2] + sred[3]);
        __hip_atomic_store(&partial[blk], bs,
                           __ATOMIC_RELAXED, __HIP_MEMORY_SCOPE_AGENT);
        unsigned old = __hip_atomic_fetch_add(&cnt[b], 1u,
                           __ATOMIC_ACQ_REL, __HIP_MEMORY_SCOPE_AGENT);
        if (old == RPB - 1) {
            float qsum = 0.0f;
            #pragma unroll
            for (int r = 0; r < RPB; ++r)
                qsum += __hip_atomic_load(&partial[b * RPB + r],
                           __ATOMIC_RELAXED, __HIP_MEMORY_SCOPE_AGENT);
            float cev = __hip_atomic_load(&ce[b],
                           __ATOMIC_RELAXED, __HIP_MEMORY_SCOPE_AGENT);
            out[b] = cev + 0.5f * qsum;
        }
    }
}

// ---------------------------------------------------------------------------
extern "C" void kernel_launch(void* const* d_in, const int* in_sizes, int n_in,
                              void* d_out, int out_size, void* d_ws, size_t ws_size,
                              hipStream_t stream)
{
    const float* m       = (const float*)d_in[0];
    const float* k       = (const float*)d_in[1];
    const int*   targets = (const int*)d_in[2];
    float*       out     = (float*)d_out;

    // workspace: ce[BB] | partial[BB*RPB] | cnt[BB]
    float*        ce      = (float*)d_ws;
    float*        partial = ce + BB;
    unsigned int* cnt     = (unsigned int*)(partial + (size_t)BB * RPB);

    hipMemsetAsync(cnt, 0, BB * sizeof(unsigned int), stream);
    fused_all_kernel<<<BB * RPB, 256, 0, stream>>>(m, k, targets, ce, partial, cnt, out);
}

// Round 4
// 85.568 us; speedup vs baseline: 2.1448x; 2.1448x over previous
//
#include <hip/hip_runtime.h>

#define BB    128          // batch
#define NN    1024         // vocab / matrix dim
#define RPB   16           // blocks per batch
#define ROWS  (NN / RPB)   // 64 rows of K per block
#define STAGE 2            // K rows prefetched into LDS via global_load_lds

typedef float f4 __attribute__((ext_vector_type(4)));

// async 16B/lane global->LDS, no VGPR round trip. lds base must be
// wave-uniform; HW writes base + lane*16.
__device__ __forceinline__ void gload_lds16(const float* g, float* l) {
    __builtin_amdgcn_global_load_lds(
        (const __attribute__((address_space(1))) void*)g,
        (__attribute__((address_space(3))) void*)l, 16, 0, 0);
}

// ---------------------------------------------------------------------------
// Kernel 1 (block (b, rb)):
//   1. issue STAGE rows of its K slice as global_load_lds (zero-VGPR prefetch
//      that keeps HBM busy during the softmax prologue),
//   2. recompute softmax(m[b]) (4 KB, L2-resident across the 16 blocks),
//   3. consume staged rows from LDS, stream remaining rows NT from global,
//      accumulating sum_{n,m} k[n,m] * p[n] * (delta(n,m) - p[m]),
//   4. write per-block partial; rb==0 writes ce[b].
// ---------------------------------------------------------------------------
__global__ __launch_bounds__(256) void fused_quad_kernel(
    const float* __restrict__ m, const float* __restrict__ k,
    const int* __restrict__ targets,
    float* __restrict__ ce, float* __restrict__ partial)
{
    const int blk = blockIdx.x;
    const int b   = blk >> 4;        // blk / RPB
    const int rb  = blk & (RPB - 1); // blk % RPB
    const int tid = threadIdx.x;

    __shared__ float sp[NN];
    __shared__ float stage[STAGE * NN];
    __shared__ float sred[4];

    const int n0 = rb * ROWS;
    const float* krow0 = k + ((size_t)b * NN + n0) * NN;

    // ---- issue LDS prefetch of rows 0..STAGE-1 (fire-and-forget) ----
    {
        const int wave = tid >> 6;
        #pragma unroll
        for (int j = 0; j < STAGE; ++j)
            gload_lds16(krow0 + (size_t)j * NN + 4 * tid,
                        stage + j * NN + wave * 256);
    }

    // ---- softmax over m[b] ----
    const float* mb = m + (size_t)b * NN;
    float4 v = reinterpret_cast<const float4*>(mb)[tid];

    float mx = fmaxf(fmaxf(v.x, v.y), fmaxf(v.z, v.w));
    #pragma unroll
    for (int off = 32; off > 0; off >>= 1) mx = fmaxf(mx, __shfl_down(mx, off));
    if ((tid & 63) == 0) sred[tid >> 6] = mx;
    __syncthreads();
    mx = fmaxf(fmaxf(sred[0], sred[1]), fmaxf(sred[2], sred[3]));
    __syncthreads();

    float e0 = expf(v.x - mx), e1 = expf(v.y - mx);
    float e2 = expf(v.z - mx), e3 = expf(v.w - mx);
    float s = (e0 + e1) + (e2 + e3);
    #pragma unroll
    for (int off = 32; off > 0; off >>= 1) s += __shfl_down(s, off);
    if ((tid & 63) == 0) sred[tid >> 6] = s;
    __syncthreads();
    s = (sred[0] + sred[1]) + (sred[2] + sred[3]);

    const float inv = 1.0f / s;
    const float pm0 = e0 * inv, pm1 = e1 * inv, pm2 = e2 * inv, pm3 = e3 * inv;
    reinterpret_cast<float4*>(sp)[tid] = make_float4(pm0, pm1, pm2, pm3);

    if (rb == 0 && tid == 0)
        ce[b] = mx + logf(s) - mb[targets[b]];

    // stage rows + sp both visible after: drain DMA, then barrier
    asm volatile("s_waitcnt vmcnt(0)" ::: "memory");
    __syncthreads();

    const int m0 = 4 * tid;
    float acc = 0.0f;

    // ---- consume staged rows from LDS ----
    #pragma unroll
    for (int j = 0; j < STAGE; ++j) {
        const int n = n0 + j;
        f4    k4 = reinterpret_cast<const f4*>(stage)[j * (NN / 4) + tid];
        float pn = sp[n];
        float d0 = (n == m0    ) ? 1.0f : 0.0f;
        float d1 = (n == m0 + 1) ? 1.0f : 0.0f;
        float d2 = (n == m0 + 2) ? 1.0f : 0.0f;
        float d3 = (n == m0 + 3) ? 1.0f : 0.0f;
        acc += pn * (k4.x * (d0 - pm0) + k4.y * (d1 - pm1) +
                     k4.z * (d2 - pm2) + k4.w * (d3 - pm3));
    }

    // ---- stream remaining rows non-temporally ----
    const f4* kp = reinterpret_cast<const f4*>(krow0) + tid;
    #pragma unroll 8
    for (int i = STAGE; i < ROWS; ++i) {
        const int n = n0 + i;
        f4    k4 = __builtin_nontemporal_load(kp + (size_t)i * (NN / 4));
        float pn = sp[n];
        float d0 = (n == m0    ) ? 1.0f : 0.0f;
        float d1 = (n == m0 + 1) ? 1.0f : 0.0f;
        float d2 = (n == m0 + 2) ? 1.0f : 0.0f;
        float d3 = (n == m0 + 3) ? 1.0f : 0.0f;
        acc += pn * (k4.x * (d0 - pm0) + k4.y * (d1 - pm1) +
                     k4.z * (d2 - pm2) + k4.w * (d3 - pm3));
    }

    // ---- block reduce ----
    #pragma unroll
    for (int off = 32; off > 0; off >>= 1) acc += __shfl_down(acc, off);
    __syncthreads();   // sred reuse safety
    if ((tid & 63) == 0) sred[tid >> 6] = acc;
    __syncthreads();
    if (tid == 0) partial[blk] = (sred[0] + sred[1]) + (sred[2] + sred[3]);
}

// ---------------------------------------------------------------------------
// out[b] = ce[b] + 0.5 * sum_r partial[b*RPB + r]
// ---------------------------------------------------------------------------
__global__ void finalize_kernel(const float* __restrict__ ce,
                                const float* __restrict__ partial,
                                float* __restrict__ out)
{
    const int b = threadIdx.x;
    if (b < BB) {
        const f4* pp = reinterpret_cast<const f4*>(partial + b * RPB);
        f4 a = pp[0], c = pp[1], d = pp[2], e = pp[3];
        float s = ((a.x + a.y) + (a.z + a.w)) + ((c.x + c.y) + (c.z + c.w)) +
                  ((d.x + d.y) + (d.z + d.w)) + ((e.x + e.y) + (e.z + e.w));
        out[b] = ce[b] + 0.5f * s;
    }
}

// ---------------------------------------------------------------------------
extern "C" void kernel_launch(void* const* d_in, const int* in_sizes, int n_in,
                              void* d_out, int out_size, void* d_ws, size_t ws_size,
                              hipStream_t stream)
{
    const float* m       = (const float*)d_in[0];
    const float* k       = (const float*)d_in[1];
    const int*   targets = (const int*)d_in[2];
    float*       out     = (float*)d_out;

    // workspace: ce[BB] | partial[BB*RPB]
    float* ce      = (float*)d_ws;
    float* partial = ce + BB;

    fused_quad_kernel<<<BB * RPB, 256, 0, stream>>>(m, k, targets, ce, partial);
    finalize_kernel<<<1, 128, 0, stream>>>(ce, partial, out);
}

// Round 5
// 83.949 us; speedup vs baseline: 2.1861x; 1.0193x over previous
//
#include <hip/hip_runtime.h>

#define BB    128          // batch
#define NN    1024         // vocab / matrix dim
#define RPB   32           // blocks per batch (2x oversubscription: 4096 blocks)
#define ROWS  (NN / RPB)   // 32 rows of K per block

typedef float f4 __attribute__((ext_vector_type(4)));

// ---------------------------------------------------------------------------
// Block (b, rb): recompute softmax(m[b]) (4 KB, L2-resident across the 32
// blocks of the batch), then stream its 32-row slice of K non-temporally,
// accumulating sum_{n,m} k[n,m] * p[n] * (delta(n,m) - p[m]).
// rb==0 also writes ce[b].  launch_bounds(256,8) pins VGPR<=64 so 8 blocks/CU.
// ---------------------------------------------------------------------------
__global__ __launch_bounds__(256, 8) void fused_quad_kernel(
    const float* __restrict__ m, const float* __restrict__ k,
    const int* __restrict__ targets,
    float* __restrict__ ce, float* __restrict__ partial)
{
    const int blk = blockIdx.x;
    const int b   = blk / RPB;
    const int rb  = blk % RPB;
    const int tid = threadIdx.x;

    __shared__ float sp[NN];
    __shared__ float sred[4];

    // ---- softmax over m[b] (each thread owns 4 contiguous elements) ----
    const float* mb = m + (size_t)b * NN;
    float4 v = reinterpret_cast<const float4*>(mb)[tid];

    float mx = fmaxf(fmaxf(v.x, v.y), fmaxf(v.z, v.w));
    #pragma unroll
    for (int off = 32; off > 0; off >>= 1) mx = fmaxf(mx, __shfl_down(mx, off));
    if ((tid & 63) == 0) sred[tid >> 6] = mx;
    __syncthreads();
    mx = fmaxf(fmaxf(sred[0], sred[1]), fmaxf(sred[2], sred[3]));
    __syncthreads();

    float e0 = expf(v.x - mx), e1 = expf(v.y - mx);
    float e2 = expf(v.z - mx), e3 = expf(v.w - mx);
    float s = (e0 + e1) + (e2 + e3);
    #pragma unroll
    for (int off = 32; off > 0; off >>= 1) s += __shfl_down(s, off);
    if ((tid & 63) == 0) sred[tid >> 6] = s;
    __syncthreads();
    s = (sred[0] + sred[1]) + (sred[2] + sred[3]);

    const float inv = 1.0f / s;
    const float pm0 = e0 * inv, pm1 = e1 * inv, pm2 = e2 * inv, pm3 = e3 * inv;
    reinterpret_cast<float4*>(sp)[tid] = make_float4(pm0, pm1, pm2, pm3);
    __syncthreads();

    if (rb == 0 && tid == 0)
        ce[b] = mx + logf(s) - mb[targets[b]];

    // ---- stream this block's rows of K non-temporally ----
    const int m0 = 4 * tid;
    const int n0 = rb * ROWS;
    const f4* kp = reinterpret_cast<const f4*>(k + ((size_t)b * NN + n0) * NN) + tid;

    float acc = 0.0f;
    #pragma unroll 8
    for (int i = 0; i < ROWS; ++i) {
        const int n = n0 + i;
        f4    k4 = __builtin_nontemporal_load(kp + (size_t)i * (NN / 4));
        float pn = sp[n];
        float d0 = (n == m0    ) ? 1.0f : 0.0f;
        float d1 = (n == m0 + 1) ? 1.0f : 0.0f;
        float d2 = (n == m0 + 2) ? 1.0f : 0.0f;
        float d3 = (n == m0 + 3) ? 1.0f : 0.0f;
        acc += pn * (k4.x * (d0 - pm0) + k4.y * (d1 - pm1) +
                     k4.z * (d2 - pm2) + k4.w * (d3 - pm3));
    }

    // ---- block reduce ----
    #pragma unroll
    for (int off = 32; off > 0; off >>= 1) acc += __shfl_down(acc, off);
    __syncthreads();   // sred reuse safety
    if ((tid & 63) == 0) sred[tid >> 6] = acc;
    __syncthreads();
    if (tid == 0) partial[blk] = (sred[0] + sred[1]) + (sred[2] + sred[3]);
}

// ---------------------------------------------------------------------------
// out[b] = ce[b] + 0.5 * sum_r partial[b*RPB + r]
// ---------------------------------------------------------------------------
__global__ void finalize_kernel(const float* __restrict__ ce,
                                const float* __restrict__ partial,
                                float* __restrict__ out)
{
    const int b = threadIdx.x;
    if (b < BB) {
        const f4* pp = reinterpret_cast<const f4*>(partial + b * RPB);
        float s = 0.0f;
        #pragma unroll
        for (int r = 0; r < RPB / 4; ++r) {
            f4 a = pp[r];
            s += (a.x + a.y) + (a.z + a.w);
        }
        out[b] = ce[b] + 0.5f * s;
    }
}

// ---------------------------------------------------------------------------
extern "C" void kernel_launch(void* const* d_in, const int* in_sizes, int n_in,
                              void* d_out, int out_size, void* d_ws, size_t ws_size,
                              hipStream_t stream)
{
    const float* m       = (const float*)d_in[0];
    const float* k       = (const float*)d_in[1];
    const int*   targets = (const int*)d_in[2];
    float*       out     = (float*)d_out;

    // workspace: ce[BB] | partial[BB*RPB]
    float* ce      = (float*)d_ws;
    float* partial = ce + BB;

    fused_quad_kernel<<<BB * RPB, 256, 0, stream>>>(m, k, targets, ce, partial);
    finalize_kernel<<<1, 128, 0, stream>>>(ce, partial, out);
}